// Round 7
// baseline (1047.702 us; speedup 1.0000x reference)
//
#include <hip/hip_runtime.h>
#include <math.h>

#define N_WIRES 8
#define N_LAYERS 6
#define NG 49          // grid per axis (frequencies |n|<=24 -> 49 samples exact)
#define NG2 (NG * NG)  // 2401
#define FPAD 52        // padded row length for F (13 x float4)
#define NBLK 1024      // 4 blocks/CU x 256 CUs: co-resident by construction
#define NTHR 256

// ws layout (bytes):
//   cnt : [0, 256)        global-barrier counter (zeroed via hipMemsetAsync)
//   E   : [256, +76832)   8 x 2401 floats (grid EVs, [i][a*49+b])
//   G   : next 76832      8 x 49 x 49 floats (intermediate DFT)
//   F   : next 81536      8 x 49 x FPAD floats (2D Fourier coeffs * pi)
#define WS_E_OFF 256
#define WS_G_OFF (WS_E_OFF + 8 * NG2 * 4)
#define WS_F_OFF (WS_G_OFF + 8 * NG2 * 4)

// ---------------------------------------------------------------------------
// Device-scope global barrier. Safe because all NBLK blocks are co-resident
// (__launch_bounds__(256,4) forces VGPR<=128 -> 4 blocks/CU capacity).
// Monotonic counter; call k waits until counter reaches k*gridDim.x.
// ---------------------------------------------------------------------------
__device__ __forceinline__ void gbar(int* cnt, int target) {
    __syncthreads();
    if (threadIdx.x == 0) {
        __threadfence();  // release prior global writes (device scope)
        __hip_atomic_fetch_add(cnt, 1, __ATOMIC_ACQ_REL, __HIP_MEMORY_SCOPE_AGENT);
        while (__hip_atomic_load(cnt, __ATOMIC_ACQUIRE, __HIP_MEMORY_SCOPE_AGENT) < target) {
            __builtin_amdgcn_s_sleep(2);
        }
        __threadfence();  // acquire other blocks' writes
    }
    __syncthreads();
}

// ---------------------------------------------------------------------------
// Per (layer,wire) fused-gate tables U,V with Gate = c*U + s*V
// ((c,s)=cos/sin(x0/2) even wires, (x1/2) odd wires).
// ---------------------------------------------------------------------------
__device__ __forceinline__ void compute_uv_lds(const float* __restrict__ w, float* uv, int t) {
    if (t >= N_LAYERS * N_WIRES) return;
    int i = t & 7;
    float wx = w[t * 3 + 0], wy = w[t * 3 + 1], wz = w[t * 3 + 2];
    float sx, cx, sy, cy, sz, cz;
    sincosf(0.5f * wx, &sx, &cx);
    sincosf(0.5f * wy, &sy, &cy);
    sincosf(0.5f * wz, &sz, &cz);
    float A00r = cy * cx, A00i = sy * sx;
    float A01r = -sy * cx, A01i = -cy * sx;
    float A10r = sy * cx, A10i = -cy * sx;
    float A11r = cy * cx, A11i = -sy * sx;
    float U00r = A00r * cz + A00i * sz, U00i = A00i * cz - A00r * sz;
    float U01r = A01r * cz + A01i * sz, U01i = A01i * cz - A01r * sz;
    float U10r = A10r * cz - A10i * sz, U10i = A10i * cz + A10r * sz;
    float U11r = A11r * cz - A11i * sz, U11i = A11i * cz + A11r * sz;
    float V00r, V00i, V01r, V01i, V10r, V10i, V11r, V11i;
    if ((i & 1) == 0) {
        V00r = U01i; V00i = -U01r;
        V01r = U00i; V01i = -U00r;
        V10r = U11i; V10i = -U11r;
        V11r = U10i; V11i = -U10r;
    } else {
        V00r = U01r;  V00i = U01i;
        V01r = -U00r; V01i = -U00i;
        V10r = U11r;  V10i = U11i;
        V11r = -U10r; V11i = -U10i;
    }
    float* o = uv + t * 16;
    o[0] = U00r; o[1] = U00i; o[2] = U01r; o[3] = U01i;
    o[4] = U10r; o[5] = U10i; o[6] = U11r; o[7] = U11i;
    o[8] = V00r; o[9] = V00i; o[10] = V01r; o[11] = V01i;
    o[12] = V10r; o[13] = V10i; o[14] = V11r; o[15] = V11i;
}

// ---------------------------------------------------------------------------
// One wave simulates one grid point (validated round-1/5 body).
// ---------------------------------------------------------------------------
__device__ void sim_point(const float* uv, int lane, int g, float* __restrict__ E) {
    const int ga = (g * 1338) >> 16;  // g/49, exact for g < 2404
    const int gb = g - ga * NG;
    const float step = (float)(2.0 * M_PI / 49.0);
    float x0 = step * (float)ga, x1 = step * (float)gb;
    float s0, c0, s1, c1;
    sincosf(0.5f * x0, &s0, &c0);
    sincosf(0.5f * x1, &s1, &c1);

    float ar[4] = {0.f, 0.f, 0.f, 0.f}, ai[4] = {0.f, 0.f, 0.f, 0.f};
    if (lane == 0) ar[0] = 1.0f;

    for (int l = 0; l < N_LAYERS; ++l) {
        const float* base = uv + l * 128;
        #pragma unroll
        for (int i = 0; i < 8; ++i) {
            const float* gm = base + i * 16;
            float ce = (i & 1) ? c1 : c0;
            float se = (i & 1) ? s1 : s0;
            float g00r = ce * gm[0] + se * gm[8],  g00i = ce * gm[1] + se * gm[9];
            float g01r = ce * gm[2] + se * gm[10], g01i = ce * gm[3] + se * gm[11];
            float g10r = ce * gm[4] + se * gm[12], g10i = ce * gm[5] + se * gm[13];
            float g11r = ce * gm[6] + se * gm[14], g11i = ce * gm[7] + se * gm[15];
            const int p = 7 - i;
            if (p >= 2) {
                const int m = 1 << (p - 2);
                const bool hi = (lane >> (p - 2)) & 1;
                float cor = hi ? g11r : g00r, coi = hi ? g11i : g00i;
                float cpr = hi ? g10r : g01r, cpi = hi ? g10i : g01i;
                #pragma unroll
                for (int j = 0; j < 4; ++j) {
                    float br = __shfl_xor(ar[j], m);
                    float bi = __shfl_xor(ai[j], m);
                    float nr = cor * ar[j] - coi * ai[j] + cpr * br - cpi * bi;
                    float ni = cor * ai[j] + coi * ar[j] + cpr * bi + cpi * br;
                    ar[j] = nr; ai[j] = ni;
                }
            } else {
                const int m = 1 << p;
                #pragma unroll
                for (int j0 = 0; j0 < 4; ++j0) {
                    if (j0 & m) continue;
                    const int j1 = j0 | m;
                    float a_r = ar[j0], a_i = ai[j0], b_r = ar[j1], b_i = ai[j1];
                    ar[j0] = g00r * a_r - g00i * a_i + g01r * b_r - g01i * b_i;
                    ai[j0] = g00r * a_i + g00i * a_r + g01r * b_i + g01i * b_r;
                    ar[j1] = g10r * a_r - g10i * a_i + g11r * b_r - g11i * b_i;
                    ai[j1] = g10r * a_i + g10i * a_r + g11r * b_i + g11i * b_r;
                }
            }
        }
        #pragma unroll
        for (int i = 0; i < 7; ++i) {
            const int pc = 7 - i, pt = 6 - i;
            if (pt >= 2) {
                const int m = 1 << (pt - 2);
                const bool ctrl = (lane >> (pc - 2)) & 1;
                #pragma unroll
                for (int j = 0; j < 4; ++j) {
                    float br = __shfl_xor(ar[j], m);
                    float bi = __shfl_xor(ai[j], m);
                    ar[j] = ctrl ? br : ar[j];
                    ai[j] = ctrl ? bi : ai[j];
                }
            } else if (pt == 1) {
                const bool ctrl = lane & 1;
                float n0r = ctrl ? ar[2] : ar[0], n0i = ctrl ? ai[2] : ai[0];
                float n2r = ctrl ? ar[0] : ar[2], n2i = ctrl ? ai[0] : ai[2];
                float n1r = ctrl ? ar[3] : ar[1], n1i = ctrl ? ai[3] : ai[1];
                float n3r = ctrl ? ar[1] : ar[3], n3i = ctrl ? ai[1] : ai[3];
                ar[0] = n0r; ai[0] = n0i; ar[1] = n1r; ai[1] = n1i;
                ar[2] = n2r; ai[2] = n2i; ar[3] = n3r; ai[3] = n3i;
            } else {
                float tr = ar[2], ti = ai[2];
                ar[2] = ar[3]; ai[2] = ai[3];
                ar[3] = tr;    ai[3] = ti;
            }
        }
    }

    float p0 = ar[0] * ar[0] + ai[0] * ai[0];
    float p1 = ar[1] * ar[1] + ai[1] * ai[1];
    float p2 = ar[2] * ar[2] + ai[2] * ai[2];
    float p3 = ar[3] * ar[3] + ai[3] * ai[3];
    float sAll = p0 + p1 + p2 + p3;

    float ev[8];
    #pragma unroll
    for (int i = 0; i < 6; ++i) ev[i] = ((lane >> (5 - i)) & 1) ? -sAll : sAll;
    ev[6] = p0 + p1 - p2 - p3;
    ev[7] = p0 - p1 + p2 - p3;

    #pragma unroll
    for (int i = 0; i < 8; ++i) {
        #pragma unroll
        for (int s = 1; s < 64; s <<= 1) ev[i] += __shfl_xor(ev[i], s);
    }

    if (lane == 0) {
        #pragma unroll
        for (int i = 0; i < 8; ++i) E[i * NG2 + g] = ev[i];
    }
}

__device__ __forceinline__ float dot52(const float* __restrict__ r, const float (&v)[FPAD]) {
    float t0 = 0.f, t1 = 0.f, t2 = 0.f, t3 = 0.f;
    #pragma unroll
    for (int l = 0; l < FPAD; l += 4) {
        t0 = fmaf(r[l + 0], v[l + 0], t0);
        t1 = fmaf(r[l + 1], v[l + 1], t1);
        t2 = fmaf(r[l + 2], v[l + 2], t2);
        t3 = fmaf(r[l + 3], v[l + 3], t3);
    }
    return (t0 + t1) + (t2 + t3);
}

// ---------------------------------------------------------------------------
// Single persistent kernel: phase1 grid sim -> barrier -> phase2a DFT(b) ->
// barrier -> phase2b DFT(a) -> barrier -> phase3 contraction.
// ---------------------------------------------------------------------------
__global__ __launch_bounds__(NTHR, 4) void qnn_all(const float* __restrict__ x,
                                                   const float* __restrict__ w,
                                                   float* __restrict__ out, int B,
                                                   int* __restrict__ cnt,
                                                   float* __restrict__ E,
                                                   float* __restrict__ G,
                                                   float* __restrict__ F) {
    __shared__ float uv[N_LAYERS * N_WIRES * 16];
    compute_uv_lds(w, uv, threadIdx.x);
    __syncthreads();

    const int tid = blockIdx.x * NTHR + threadIdx.x;
    const int TOT = gridDim.x * NTHR;          // 262144
    const int lane = threadIdx.x & 63;
    const int nwaves = TOT >> 6;               // 4096

    // ---- Phase 1: circuit eval on 49x49 grid (one wave per point) ----
    for (int g = tid >> 6; g < NG2; g += nwaves) sim_point(uv, lane, g, E);

    gbar(cnt, gridDim.x);

    // ---- Phase 2a: G[i][a][k] = sum_b E[i][a*49+b] * T[b][k] ----
    for (int t = tid; t < 8 * NG2; t += TOT) {
        const int i = t / NG2;
        const int r = t - i * NG2;
        const int a = (r * 1338) >> 16;
        const int k = r - a * NG;
        const float* Er = E + i * NG2 + a * NG;
        float acc = 0.f;
        if (k == 0) {
            for (int b = 0; b < NG; ++b) acc += Er[b];
            acc *= (1.0f / 49.0f);
        } else {
            int n = (k + 1) >> 1;
            float cs, ss;
            sincosf((float)(2.0 * M_PI / 49.0) * (float)n, &ss, &cs);
            float cb = 1.f, sb = 0.f;
            const bool use_cos = (k & 1);
            for (int b = 0; b < NG; ++b) {
                acc = fmaf(Er[b], use_cos ? cb : sb, acc);
                float cn = cb * cs - sb * ss;
                float sn = sb * cs + cb * ss;
                cb = cn; sb = sn;
            }
            acc *= (2.0f / 49.0f);
        }
        G[(i * NG + a) * NG + k] = acc;
    }

    gbar(cnt, 2 * gridDim.x);

    // ---- Phase 2b: F[i][kp][l] = pi * sum_a T[a][kp] * G[i][a][l] ----
    for (int t = tid; t < 8 * NG * FPAD; t += TOT) {
        const int i = t / (NG * FPAD);
        const int r = t - i * (NG * FPAD);
        const int kp = r / FPAD;
        const int l = r - kp * FPAD;
        const float PI = 3.14159265358979323846f;
        float acc = 0.f;
        if (l < NG) {
            if (kp == 0) {
                for (int a = 0; a < NG; ++a) acc += G[(i * NG + a) * NG + l];
                acc *= (PI / 49.0f);
            } else {
                int n = (kp + 1) >> 1;
                float cs, ss;
                sincosf((float)(2.0 * M_PI / 49.0) * (float)n, &ss, &cs);
                float ca = 1.f, sa = 0.f;
                const bool use_cos = (kp & 1);
                for (int a = 0; a < NG; ++a) {
                    acc = fmaf(G[(i * NG + a) * NG + l], use_cos ? ca : sa, acc);
                    float cn = ca * cs - sa * ss;
                    float sn = sa * cs + ca * ss;
                    ca = cn; sa = sn;
                }
                acc *= (2.0f * PI / 49.0f);
            }
        }
        F[(i * NG + kp) * FPAD + l] = acc;
    }

    gbar(cnt, 3 * gridDim.x);

    // ---- Phase 3: out[b][i] = v0(x0)^T F_i v1(x1)  (pi folded into F).
    // Slot s in [0, 2B): b = s mod B, j = s / B; this thread computes the 4
    // outputs i = 4j..4j+3 for batch element b — v1 built ONCE, reused 4x.
    // Inner loop = round-5's proven structure (VGPR 36, no concurrency bloat).
    for (int s = tid; s < 2 * B; s += TOT) {
        const int j = s / B;
        const int b = s - j * B;

        float2 xv = ((const float2*)x)[b];
        float s0, c0, s1, c1;
        sincosf(xv.x, &s0, &c0);
        sincosf(xv.y, &s1, &c1);

        float v1[FPAD];
        v1[0] = 1.0f; v1[1] = c1; v1[2] = s1;
        #pragma unroll
        for (int n = 2; n <= 24; ++n) {
            v1[2 * n - 1] = v1[2 * n - 3] * c1 - v1[2 * n - 2] * s1;
            v1[2 * n]     = v1[2 * n - 2] * c1 + v1[2 * n - 3] * s1;
        }
        v1[49] = 0.f; v1[50] = 0.f; v1[51] = 0.f;

        float res[4];
        #pragma unroll 1
        for (int p = 0; p < 4; ++p) {
            const int i = j * 4 + p;
            const float* base = F + (size_t)i * NG * FPAD;
            float acc = dot52(base, v1);  // n=0 row
            float Ck = c0, Sk = s0;
            const float* rp = base + FPAD;
            #pragma unroll 2
            for (int n = 1; n <= 24; ++n) {
                float tC = dot52(rp, v1);
                float tS = dot52(rp + FPAD, v1);
                acc = fmaf(Ck, tC, acc);
                acc = fmaf(Sk, tS, acc);
                float Cn = Ck * c0 - Sk * s0;
                float Sn = Sk * c0 + Ck * s0;
                Ck = Cn; Sk = Sn;
                rp += 2 * FPAD;
            }
            res[p] = acc;
        }

        float4* o = (float4*)(out + (size_t)b * 8 + j * 4);
        *o = make_float4(res[0], res[1], res[2], res[3]);
    }
}

extern "C" void kernel_launch(void* const* d_in, const int* in_sizes, int n_in,
                              void* d_out, int out_size, void* d_ws, size_t ws_size,
                              hipStream_t stream) {
    (void)n_in; (void)out_size; (void)ws_size;
    const float* x = (const float*)d_in[0];
    const float* w = (const float*)d_in[1];
    float* out = (float*)d_out;
    char* ws = (char*)d_ws;
    int* cnt = (int*)ws;
    float* E = (float*)(ws + WS_E_OFF);
    float* G = (float*)(ws + WS_G_OFF);
    float* F = (float*)(ws + WS_F_OFF);
    const int B = in_sizes[0] / 2;

    hipMemsetAsync(cnt, 0, 256, stream);  // zero the barrier counter (ws is poisoned)
    hipLaunchKernelGGL(qnn_all, dim3(NBLK), dim3(NTHR), 0, stream,
                       x, w, out, B, cnt, E, G, F);
}

// Round 8
// 150.826 us; speedup vs baseline: 6.9464x; 6.9464x over previous
//
#include <hip/hip_runtime.h>
#include <math.h>

#define N_WIRES 8
#define N_LAYERS 6
#define NG 49          // grid per axis (frequencies |n|<=24 -> 49 samples exact)
#define NG2 (NG * NG)  // 2401
#define FPAD 52        // padded row length for F rows (26 x half2)

// ws layout (bytes):
//   E  : [0,      76832)    8 x 2401 floats (grid EVs, [i][a*49+b])
//   G  : [76832,  153664)   8 x 49 x 49 floats (intermediate DFT)
//   F  : [153664, +40768)   8 x 49 x FPAD _Float16 (2D Fourier coeffs * pi)
#define WS_E_OFF 0
#define WS_G_OFF 76832
#define WS_F_OFF 153664

typedef _Float16 half2v __attribute__((ext_vector_type(2)));

// ---------------------------------------------------------------------------
// Per (layer,wire) fused-gate tables U,V with Gate = c*U + s*V
// ((c,s)=cos/sin(x0/2) even wires, (x1/2) odd wires). Computed per-block in
// LDS (48 threads, trivial) to save a launch.
// ---------------------------------------------------------------------------
__device__ __forceinline__ void compute_uv_lds(const float* __restrict__ w, float* uv, int t) {
    if (t >= N_LAYERS * N_WIRES) return;
    int i = t & 7;
    float wx = w[t * 3 + 0], wy = w[t * 3 + 1], wz = w[t * 3 + 2];
    float sx, cx, sy, cy, sz, cz;
    sincosf(0.5f * wx, &sx, &cx);
    sincosf(0.5f * wy, &sy, &cy);
    sincosf(0.5f * wz, &sz, &cz);
    float A00r = cy * cx, A00i = sy * sx;
    float A01r = -sy * cx, A01i = -cy * sx;
    float A10r = sy * cx, A10i = -cy * sx;
    float A11r = cy * cx, A11i = -sy * sx;
    float U00r = A00r * cz + A00i * sz, U00i = A00i * cz - A00r * sz;
    float U01r = A01r * cz + A01i * sz, U01i = A01i * cz - A01r * sz;
    float U10r = A10r * cz - A10i * sz, U10i = A10i * cz + A10r * sz;
    float U11r = A11r * cz - A11i * sz, U11i = A11i * cz + A11r * sz;
    float V00r, V00i, V01r, V01i, V10r, V10i, V11r, V11i;
    if ((i & 1) == 0) {
        V00r = U01i; V00i = -U01r;
        V01r = U00i; V01i = -U00r;
        V10r = U11i; V10i = -U11r;
        V11r = U10i; V11i = -U10r;
    } else {
        V00r = U01r;  V00i = U01i;
        V01r = -U00r; V01i = -U00i;
        V10r = U11r;  V10i = U11i;
        V11r = -U10r; V11i = -U10i;
    }
    float* o = uv + t * 16;
    o[0] = U00r; o[1] = U00i; o[2] = U01r; o[3] = U01i;
    o[4] = U10r; o[5] = U10i; o[6] = U11r; o[7] = U11i;
    o[8] = V00r; o[9] = V00i; o[10] = V01r; o[11] = V01i;
    o[12] = V10r; o[13] = V10i; o[14] = V11r; o[15] = V11i;
}

// ---------------------------------------------------------------------------
// Grid circuit eval: one wave per grid point g=a*49+b ->
// (x0,x1)=(2*pi*a/49, 2*pi*b/49). Writes E[i][g].
// ---------------------------------------------------------------------------
__global__ __launch_bounds__(256) void qnn_grid_kernel(const float* __restrict__ w,
                                                       float* __restrict__ E) {
    __shared__ float uv[N_LAYERS * N_WIRES * 16];
    compute_uv_lds(w, uv, threadIdx.x);
    __syncthreads();

    const int lane = threadIdx.x & 63;
    const int g = blockIdx.x * (blockDim.x >> 6) + (threadIdx.x >> 6);
    if (g >= NG2) return;

    const int ga = (g * 1338) >> 16;  // g/49, exact for g < 2404
    const int gb = g - ga * NG;
    const float step = (float)(2.0 * M_PI / 49.0);
    float x0 = step * (float)ga, x1 = step * (float)gb;
    float s0, c0, s1, c1;
    sincosf(0.5f * x0, &s0, &c0);
    sincosf(0.5f * x1, &s1, &c1);

    float ar[4] = {0.f, 0.f, 0.f, 0.f}, ai[4] = {0.f, 0.f, 0.f, 0.f};
    if (lane == 0) ar[0] = 1.0f;

    for (int l = 0; l < N_LAYERS; ++l) {
        const float* base = uv + l * 128;
        #pragma unroll
        for (int i = 0; i < 8; ++i) {
            const float* gm = base + i * 16;
            float ce = (i & 1) ? c1 : c0;
            float se = (i & 1) ? s1 : s0;
            float g00r = ce * gm[0] + se * gm[8],  g00i = ce * gm[1] + se * gm[9];
            float g01r = ce * gm[2] + se * gm[10], g01i = ce * gm[3] + se * gm[11];
            float g10r = ce * gm[4] + se * gm[12], g10i = ce * gm[5] + se * gm[13];
            float g11r = ce * gm[6] + se * gm[14], g11i = ce * gm[7] + se * gm[15];
            const int p = 7 - i;
            if (p >= 2) {
                const int m = 1 << (p - 2);
                const bool hi = (lane >> (p - 2)) & 1;
                float cor = hi ? g11r : g00r, coi = hi ? g11i : g00i;
                float cpr = hi ? g10r : g01r, cpi = hi ? g10i : g01i;
                #pragma unroll
                for (int j = 0; j < 4; ++j) {
                    float br = __shfl_xor(ar[j], m);
                    float bi = __shfl_xor(ai[j], m);
                    float nr = cor * ar[j] - coi * ai[j] + cpr * br - cpi * bi;
                    float ni = cor * ai[j] + coi * ar[j] + cpr * bi + cpi * br;
                    ar[j] = nr; ai[j] = ni;
                }
            } else {
                const int m = 1 << p;
                #pragma unroll
                for (int j0 = 0; j0 < 4; ++j0) {
                    if (j0 & m) continue;
                    const int j1 = j0 | m;
                    float a_r = ar[j0], a_i = ai[j0], b_r = ar[j1], b_i = ai[j1];
                    ar[j0] = g00r * a_r - g00i * a_i + g01r * b_r - g01i * b_i;
                    ai[j0] = g00r * a_i + g00i * a_r + g01r * b_i + g01i * b_r;
                    ar[j1] = g10r * a_r - g10i * a_i + g11r * b_r - g11i * b_i;
                    ai[j1] = g10r * a_i + g10i * a_r + g11r * b_i + g11i * b_r;
                }
            }
        }
        #pragma unroll
        for (int i = 0; i < 7; ++i) {
            const int pc = 7 - i, pt = 6 - i;
            if (pt >= 2) {
                const int m = 1 << (pt - 2);
                const bool ctrl = (lane >> (pc - 2)) & 1;
                #pragma unroll
                for (int j = 0; j < 4; ++j) {
                    float br = __shfl_xor(ar[j], m);
                    float bi = __shfl_xor(ai[j], m);
                    ar[j] = ctrl ? br : ar[j];
                    ai[j] = ctrl ? bi : ai[j];
                }
            } else if (pt == 1) {
                const bool ctrl = lane & 1;
                float n0r = ctrl ? ar[2] : ar[0], n0i = ctrl ? ai[2] : ai[0];
                float n2r = ctrl ? ar[0] : ar[2], n2i = ctrl ? ai[0] : ai[2];
                float n1r = ctrl ? ar[3] : ar[1], n1i = ctrl ? ai[3] : ai[1];
                float n3r = ctrl ? ar[1] : ar[3], n3i = ctrl ? ai[1] : ai[3];
                ar[0] = n0r; ai[0] = n0i; ar[1] = n1r; ai[1] = n1i;
                ar[2] = n2r; ai[2] = n2i; ar[3] = n3r; ai[3] = n3i;
            } else {
                float tr = ar[2], ti = ai[2];
                ar[2] = ar[3]; ai[2] = ai[3];
                ar[3] = tr;    ai[3] = ti;
            }
        }
    }

    float p0 = ar[0] * ar[0] + ai[0] * ai[0];
    float p1 = ar[1] * ar[1] + ai[1] * ai[1];
    float p2 = ar[2] * ar[2] + ai[2] * ai[2];
    float p3 = ar[3] * ar[3] + ai[3] * ai[3];
    float sAll = p0 + p1 + p2 + p3;

    float ev[8];
    #pragma unroll
    for (int i = 0; i < 6; ++i) ev[i] = ((lane >> (5 - i)) & 1) ? -sAll : sAll;
    ev[6] = p0 + p1 - p2 - p3;
    ev[7] = p0 - p1 + p2 - p3;

    #pragma unroll
    for (int i = 0; i < 8; ++i) {
        #pragma unroll
        for (int s = 1; s < 64; s <<= 1) ev[i] += __shfl_xor(ev[i], s);
    }

    if (lane == 0) {
        #pragma unroll
        for (int i = 0; i < 8; ++i) E[i * NG2 + g] = ev[i];
    }
}

// ---------------------------------------------------------------------------
// Stage 3a: G[i][a][k] = sum_b E[i][a*49+b] * T[b][k]
// T[b][0]=1/49, T[b][2n-1]=(2/49)cos(2pi n b/49), T[b][2n]=(2/49)sin(...)
// block 64 threads = k; grid (49, 8) = (a, i).
// ---------------------------------------------------------------------------
__global__ void dft_b(const float* __restrict__ E, float* __restrict__ G) {
    const int a = blockIdx.x, i = blockIdx.y, k = threadIdx.x;
    if (k >= NG) return;
    const float* Er = E + i * NG2 + a * NG;
    float acc = 0.f;
    if (k == 0) {
        for (int b = 0; b < NG; ++b) acc += Er[b];
        acc *= (1.0f / 49.0f);
    } else {
        int n = (k + 1) >> 1;
        float cs, ss;
        sincosf((float)(2.0 * M_PI / 49.0) * (float)n, &ss, &cs);
        float cb = 1.f, sb = 0.f;
        const bool use_cos = (k & 1);
        for (int b = 0; b < NG; ++b) {
            acc = fmaf(Er[b], use_cos ? cb : sb, acc);
            float cn = cb * cs - sb * ss;
            float sn = sb * cs + cb * ss;
            cb = cn; sb = sn;
        }
        acc *= (2.0f / 49.0f);
    }
    G[(i * NG + a) * NG + k] = acc;
}

// ---------------------------------------------------------------------------
// Stage 3b: F[i][kp][l] = pi * sum_a T[a][kp] * G[i][a][l], stored as f16
// (pi folded; fp32 accumulate, one rounding on store). Pad l>=49 is zero.
// block 64 threads = l; grid (49, 8) = (kp, i).
// ---------------------------------------------------------------------------
__global__ void dft_a(const float* __restrict__ G, _Float16* __restrict__ F) {
    const int kp = blockIdx.x, i = blockIdx.y, l = threadIdx.x;
    if (l >= FPAD) return;
    const float PI = 3.14159265358979323846f;
    float acc = 0.f;
    if (l < NG) {
        if (kp == 0) {
            for (int a = 0; a < NG; ++a) acc += G[(i * NG + a) * NG + l];
            acc *= (PI / 49.0f);
        } else {
            int n = (kp + 1) >> 1;
            float cs, ss;
            sincosf((float)(2.0 * M_PI / 49.0) * (float)n, &ss, &cs);
            float ca = 1.f, sa = 0.f;
            const bool use_cos = (kp & 1);
            for (int a = 0; a < NG; ++a) {
                acc = fmaf(G[(i * NG + a) * NG + l], use_cos ? ca : sa, acc);
                float cn = ca * cs - sa * ss;
                float sn = sa * cs + ca * ss;
                ca = cn; sa = sn;
            }
            acc *= (2.0f * PI / 49.0f);
        }
    }
    F[(i * NG + kp) * FPAD + l] = (_Float16)acc;
}

// ---------------------------------------------------------------------------
// Final contraction: out[b][i] = v0(x0)^T F_i v1(x1)   (pi already in F).
// Round-5 proven structure (grid (B/256,4), 2 outputs/thread, 8192 waves =
// 8/SIMD), with the dot engine swapped to v_dot2_f32_f16: 26 dot2 per row
// instead of 52 v_fma — VALU work and scalar-fetch both halve, fp32 acc.
// ---------------------------------------------------------------------------
#if __has_builtin(__builtin_amdgcn_fdot2)
#define DOT2(a, b, c) __builtin_amdgcn_fdot2((a), (b), (c), false)
#else
#define DOT2(a, b, c) ((float)(a).x * (float)(b).x + (float)(a).y * (float)(b).y + (c))
#endif

__device__ __forceinline__ float dot26(const half2v* __restrict__ r, const half2v (&v)[26]) {
    float t0 = 0.f, t1 = 0.f;
    #pragma unroll
    for (int l = 0; l < 26; l += 2) {
        t0 = DOT2(r[l], v[l], t0);
        t1 = DOT2(r[l + 1], v[l + 1], t1);
    }
    return t0 + t1;
}

__global__ __launch_bounds__(256) void contract_kernel(const float* __restrict__ x,
                                                       const _Float16* __restrict__ F,
                                                       float* __restrict__ out, int B) {
    const int b = blockIdx.x * 256 + threadIdx.x;
    const int i0 = blockIdx.y * 2;
    if (b >= B) return;

    float2 xv = ((const float2*)x)[b];
    float s0, c0, s1, c1;
    sincosf(xv.x, &s0, &c0);
    sincosf(xv.y, &s1, &c1);

    // v1 recurrence in fp32, then one-time convert to 26 half2
    float v1[FPAD];
    v1[0] = 1.0f; v1[1] = c1; v1[2] = s1;
    #pragma unroll
    for (int n = 2; n <= 24; ++n) {
        v1[2 * n - 1] = v1[2 * n - 3] * c1 - v1[2 * n - 2] * s1;
        v1[2 * n]     = v1[2 * n - 2] * c1 + v1[2 * n - 3] * s1;
    }
    v1[49] = 0.f; v1[50] = 0.f; v1[51] = 0.f;

    half2v v1h[26];
    #pragma unroll
    for (int l = 0; l < 26; ++l) {
        half2v h;
        h.x = (_Float16)v1[2 * l];
        h.y = (_Float16)v1[2 * l + 1];
        v1h[l] = h;
    }

    const half2v* base0 = (const half2v*)(F + (size_t)i0 * NG * FPAD);
    const half2v* base1 = base0 + NG * (FPAD / 2);

    float acc0 = dot26(base0, v1h);  // n=0 row
    float acc1 = dot26(base1, v1h);
    float Ck = c0, Sk = s0;
    const half2v* rp0 = base0 + (FPAD / 2);
    const half2v* rp1 = base1 + (FPAD / 2);

    #pragma unroll 2
    for (int n = 1; n <= 24; ++n) {
        float tC0 = dot26(rp0, v1h);
        float tS0 = dot26(rp0 + (FPAD / 2), v1h);
        float tC1 = dot26(rp1, v1h);
        float tS1 = dot26(rp1 + (FPAD / 2), v1h);
        acc0 = fmaf(Ck, tC0, acc0);
        acc0 = fmaf(Sk, tS0, acc0);
        acc1 = fmaf(Ck, tC1, acc1);
        acc1 = fmaf(Sk, tS1, acc1);
        float Cn = Ck * c0 - Sk * s0;
        float Sn = Sk * c0 + Ck * s0;
        Ck = Cn; Sk = Sn;
        rp0 += FPAD;  // 2 rows of 26 half2
        rp1 += FPAD;
    }

    float* o = out + (size_t)b * 8 + i0;
    o[0] = acc0;
    o[1] = acc1;
}

extern "C" void kernel_launch(void* const* d_in, const int* in_sizes, int n_in,
                              void* d_out, int out_size, void* d_ws, size_t ws_size,
                              hipStream_t stream) {
    (void)n_in; (void)out_size; (void)ws_size;
    const float* x = (const float*)d_in[0];
    const float* w = (const float*)d_in[1];
    float* out = (float*)d_out;
    char* ws = (char*)d_ws;
    float* E = (float*)(ws + WS_E_OFF);
    float* G = (float*)(ws + WS_G_OFF);
    _Float16* F = (_Float16*)(ws + WS_F_OFF);
    const int B = in_sizes[0] / 2;

    hipLaunchKernelGGL(qnn_grid_kernel, dim3((NG2 + 3) / 4), dim3(256), 0, stream, w, E);
    hipLaunchKernelGGL(dft_b, dim3(NG, 8), dim3(64), 0, stream, E, G);
    hipLaunchKernelGGL(dft_a, dim3(NG, 8), dim3(64), 0, stream, G, F);
    hipLaunchKernelGGL(contract_kernel, dim3((B + 255) / 256, 4), dim3(256), 0, stream,
                       x, F, out, B);
}